// Round 6
// baseline (592.028 us; speedup 1.0000x reference)
//
#include <hip/hip_runtime.h>
#include <math.h>

// Shapes (fixed for this problem)
#define HT   128
#define WD   128
#define HW   16384      // HT*WD
#define NB_B 4
#define BHW  65536      // NB_B*HW
#define CD   96
#define C3   288
#define NH   6
#define HD   16
#define HID  255
#define HID2 510
#define KK   7
#define NNB  49

// ---------------------------------------------------------------------------
// Fold LayerNorm affine into the following 1x1 conv, and store weights
// TRANSPOSED (wT[c*OS + o]) so the conv inner loop reads 16 consecutive
// uniform floats per c-step -> wide scalar loads instead of strided scalars.
//   conv(LN(x))_o = rsig * (sum_c W'[o,c] x_c - mu * S'[o]) + B'[o]
// Also transposes proj_w and pout_w into workspace.
// ---------------------------------------------------------------------------
__global__ __launch_bounds__(256) void prep_weights(
    const float* __restrict__ qkv_w, const float* __restrict__ qkv_b,
    const float* __restrict__ ln1_w, const float* __restrict__ ln1_b,
    const float* __restrict__ pin_w, const float* __restrict__ ln2_w,
    const float* __restrict__ ln2_b,
    const float* __restrict__ proj_w, const float* __restrict__ pout_w,
    float* __restrict__ w1t, float* __restrict__ s1, float* __restrict__ b1,
    float* __restrict__ w2t, float* __restrict__ s2, float* __restrict__ b2,
    float* __restrict__ wpt, float* __restrict__ wot)
{
    int o = blockIdx.x * 256 + threadIdx.x;          // [0, 512)
    if (o < C3) {
        float s = 0.f, bb = qkv_b[o];
        for (int c = 0; c < CD; ++c) {
            float wv = qkv_w[o*CD+c] * ln1_w[c];
            w1t[(size_t)c * C3 + o] = wv;
            s += wv;
            bb += qkv_w[o*CD+c] * ln1_b[c];
        }
        s1[o] = s; b1[o] = bb;
    }
    if (o < HID2) {
        float s = 0.f, bb = 0.f;                     // pin conv has no bias
        for (int c = 0; c < CD; ++c) {
            float wv = pin_w[o*CD+c] * ln2_w[c];
            w2t[(size_t)c * 512 + o] = wv;
            s += wv;
            bb += pin_w[o*CD+c] * ln2_b[c];
        }
        s2[o] = s; b2[o] = bb;
    } else if (o < 512) {                            // pad cols 510/511 (never stored)
        for (int c = 0; c < CD; ++c) w2t[(size_t)c * 512 + o] = 0.f;
        s2[o] = 0.f; b2[o] = 0.f;
    }
    if (o < CD) {
        for (int c = 0; c < CD; ++c)
            wpt[(size_t)c * CD + o] = proj_w[o*CD + c];
        for (int c = 0; c < HID; ++c)
            wot[(size_t)c * CD + o] = pout_w[o*HID + c];
    }
}

// Per-pixel LayerNorm stats over the 96 channels (biased variance, eps 1e-5)
// 4 pixels/thread.
__global__ __launch_bounds__(256) void ln_stats(
    const float* __restrict__ x, float* __restrict__ mu, float* __restrict__ rsig)
{
    int t  = blockIdx.x * 256 + threadIdx.x;   // quad index [0, BHW/4)
    int p4 = t * 4;
    int b = p4 >> 14, p = p4 & (HW - 1);
    const float* xp = x + (size_t)b * CD * HW + p;
    float4 s = {0.f,0.f,0.f,0.f}, s2 = {0.f,0.f,0.f,0.f};
    #pragma unroll 4
    for (int c = 0; c < CD; ++c) {
        float4 v = *(const float4*)(xp + (size_t)c * HW);
        s.x += v.x; s.y += v.y; s.z += v.z; s.w += v.w;
        s2.x = fmaf(v.x, v.x, s2.x); s2.y = fmaf(v.y, v.y, s2.y);
        s2.z = fmaf(v.z, v.z, s2.z); s2.w = fmaf(v.w, v.w, s2.w);
    }
    const float inv = 1.f / CD;
    float4 m, r;
    m.x = s.x*inv; m.y = s.y*inv; m.z = s.z*inv; m.w = s.w*inv;
    r.x = rsqrtf(s2.x*inv - m.x*m.x + 1e-5f);
    r.y = rsqrtf(s2.y*inv - m.y*m.y + 1e-5f);
    r.z = rsqrtf(s2.z*inv - m.z*m.z + 1e-5f);
    r.w = rsqrtf(s2.w*inv - m.w*m.w + 1e-5f);
    *(float4*)(mu + p4)   = m;
    *(float4*)(rsig + p4) = r;
}

// ---------------------------------------------------------------------------
// 1x1 conv (GEMM on the vector ALU).  4 pixels x 16 output channels / thread.
// Inner loop: 1 float4 vector load : 64 FMA.  Weights transposed (wT[c*OS+o]),
// block-uniform -> scalar loads.  grid = (Cout/16, BHW/1024), x-major launch
// keeps each 1024-pixel x 96-ch input tile L2-hot across all cout groups.
// EPI 0: LN-folded epilogue   out = rsig*(acc - mu*S[o]) + Bb[o]
// EPI 1: proj+residual        out = res + (acc + Bb[o]) * scale[o]
// EPI 2: pout+residual        out = res + acc * scale[o]
// ---------------------------------------------------------------------------
template<int EPI>
__global__ __launch_bounds__(256) void conv1x1(
    const float* __restrict__ in, const float* __restrict__ wT,
    int Cin, int Cout, int OS,
    const float* __restrict__ S, const float* __restrict__ Bb,
    const float* __restrict__ mu, const float* __restrict__ rsig,
    const float* __restrict__ res, const float* __restrict__ scale,
    float* __restrict__ out)
{
    int t  = blockIdx.y * 256 + threadIdx.x;   // quad index [0, BHW/4)
    int p4 = t * 4;
    int o0 = blockIdx.x * 16;
    int b = p4 >> 14, p = p4 & (HW - 1);
    const float* ip = in + (size_t)b * Cin * HW + p;
    float4 acc[16];
    #pragma unroll
    for (int u = 0; u < 16; ++u) acc[u] = {0.f,0.f,0.f,0.f};
    #pragma unroll 2
    for (int c = 0; c < Cin; ++c) {
        float4 v = *(const float4*)(ip + (size_t)c * HW);
        const float* wr = wT + (size_t)c * OS + o0;  // 16 consecutive, uniform
        #pragma unroll
        for (int u = 0; u < 16; ++u) {
            float wv = wr[u];
            acc[u].x = fmaf(v.x, wv, acc[u].x);
            acc[u].y = fmaf(v.y, wv, acc[u].y);
            acc[u].z = fmaf(v.z, wv, acc[u].z);
            acc[u].w = fmaf(v.w, wv, acc[u].w);
        }
    }
    size_t obase = (size_t)b * Cout * HW + p;
    if (EPI == 0) {
        float4 m = *(const float4*)(mu + p4);
        float4 r = *(const float4*)(rsig + p4);
        #pragma unroll
        for (int u = 0; u < 16; ++u) {
            int o = o0 + u;
            if (o < Cout) {
                float so = S[o], bo = Bb[o];
                float4 ov;
                ov.x = r.x * (acc[u].x - m.x * so) + bo;
                ov.y = r.y * (acc[u].y - m.y * so) + bo;
                ov.z = r.z * (acc[u].z - m.z * so) + bo;
                ov.w = r.w * (acc[u].w - m.w * so) + bo;
                *(float4*)(out + obase + (size_t)o * HW) = ov;
            }
        }
    } else if (EPI == 1) {
        #pragma unroll
        for (int u = 0; u < 16; ++u) {
            int o = o0 + u;
            float bo = Bb[o], sc = scale[o];
            float4 rv = *(const float4*)(res + obase + (size_t)o * HW);
            float4 ov;
            ov.x = rv.x + (acc[u].x + bo) * sc;
            ov.y = rv.y + (acc[u].y + bo) * sc;
            ov.z = rv.z + (acc[u].z + bo) * sc;
            ov.w = rv.w + (acc[u].w + bo) * sc;
            *(float4*)(out + obase + (size_t)o * HW) = ov;
        }
    } else {
        #pragma unroll
        for (int u = 0; u < 16; ++u) {
            int o = o0 + u;
            float sc = scale[o];
            float4 rv = *(const float4*)(res + obase + (size_t)o * HW);
            float4 ov;
            ov.x = rv.x + acc[u].x * sc;
            ov.y = rv.y + acc[u].y * sc;
            ov.z = rv.z + acc[u].z * sc;
            ov.w = rv.w + acc[u].w * sc;
            *(float4*)(out + obase + (size_t)o * HW) = ov;
        }
    }
}

// Depthwise 3x3, SAME zero padding, with bias (qkv path).  4 pixels/thread.
__global__ __launch_bounds__(256) void dwconv3x3(
    const float* __restrict__ in, const float* __restrict__ dwv,
    const float* __restrict__ bias, float* __restrict__ out, int Ch)
{
    int t  = blockIdx.x * 256 + threadIdx.x;   // quad within image
    int p4 = t * 4;
    int bc = blockIdx.y;                       // b*Ch + c
    int c  = bc % Ch;
    int h = p4 >> 7, wx = p4 & (WD - 1);       // wx multiple of 4; quad in one row
    const float* ip = in + (size_t)bc * HW;
    const float* wk = dwv + c * 9;
    float bz = bias[c];
    float a0 = bz, a1 = bz, a2 = bz, a3 = bz;
    #pragma unroll
    for (int ky = 0; ky < 3; ++ky) {
        int hh = h + ky - 1;
        if (hh < 0 || hh >= HT) continue;
        const float* rowp = ip + hh * WD + wx;
        float vm = (wx > 0)        ? rowp[-1] : 0.f;
        float4 v = *(const float4*)rowp;
        float vp = (wx + 4 < WD)   ? rowp[4]  : 0.f;
        float w0 = wk[ky*3+0], w1 = wk[ky*3+1], w2 = wk[ky*3+2];
        a0 = fmaf(vm,  w0, a0); a0 = fmaf(v.x, w1, a0); a0 = fmaf(v.y, w2, a0);
        a1 = fmaf(v.x, w0, a1); a1 = fmaf(v.y, w1, a1); a1 = fmaf(v.z, w2, a1);
        a2 = fmaf(v.y, w0, a2); a2 = fmaf(v.z, w1, a2); a2 = fmaf(v.w, w2, a2);
        a3 = fmaf(v.z, w0, a3); a3 = fmaf(v.w, w1, a3); a3 = fmaf(vp,  w2, a3);
    }
    float4 ov; ov.x = a0; ov.y = a1; ov.z = a2; ov.w = a3;
    *(float4*)(out + (size_t)bc * HW + p4) = ov;
}

// FFN depthwise 3x3 (no bias) fused with exact-GELU gating, 4 pixels/thread:
//   out[j] = gelu(dw(ch j)) * dw(ch j+255)
__global__ __launch_bounds__(256) void dw_gate(
    const float* __restrict__ in, const float* __restrict__ dwv,
    float* __restrict__ out)
{
    int t  = blockIdx.x * 256 + threadIdx.x;
    int p4 = t * 4;
    int bj = blockIdx.y;                       // b*HID + j
    int b = bj / HID, j = bj % HID;
    int h = p4 >> 7, wx = p4 & (WD - 1);
    const float* i1 = in + ((size_t)b * HID2 + j) * HW;
    const float* i2 = i1 + (size_t)HID * HW;
    const float* wk1 = dwv + j * 9;
    const float* wk2 = dwv + (j + HID) * 9;
    float a0=0.f,a1=0.f,a2=0.f,a3=0.f, g0=0.f,g1=0.f,g2=0.f,g3=0.f;
    #pragma unroll
    for (int ky = 0; ky < 3; ++ky) {
        int hh = h + ky - 1;
        if (hh < 0 || hh >= HT) continue;
        const float* r1 = i1 + hh * WD + wx;
        const float* r2 = i2 + hh * WD + wx;
        bool lm = (wx > 0), rp = (wx + 4 < WD);
        float um = lm ? r1[-1] : 0.f;
        float4 u = *(const float4*)r1;
        float up = rp ? r1[4] : 0.f;
        float vm = lm ? r2[-1] : 0.f;
        float4 v = *(const float4*)r2;
        float vp = rp ? r2[4] : 0.f;
        float w10 = wk1[ky*3+0], w11 = wk1[ky*3+1], w12 = wk1[ky*3+2];
        float w20 = wk2[ky*3+0], w21 = wk2[ky*3+1], w22 = wk2[ky*3+2];
        a0 = fmaf(um,  w10, a0); a0 = fmaf(u.x, w11, a0); a0 = fmaf(u.y, w12, a0);
        a1 = fmaf(u.x, w10, a1); a1 = fmaf(u.y, w11, a1); a1 = fmaf(u.z, w12, a1);
        a2 = fmaf(u.y, w10, a2); a2 = fmaf(u.z, w11, a2); a2 = fmaf(u.w, w12, a2);
        a3 = fmaf(u.z, w10, a3); a3 = fmaf(u.w, w11, a3); a3 = fmaf(up,  w12, a3);
        g0 = fmaf(vm,  w20, g0); g0 = fmaf(v.x, w21, g0); g0 = fmaf(v.y, w22, g0);
        g1 = fmaf(v.x, w20, g1); g1 = fmaf(v.y, w21, g1); g1 = fmaf(v.z, w22, g1);
        g2 = fmaf(v.y, w20, g2); g2 = fmaf(v.z, w21, g2); g2 = fmaf(v.w, w22, g2);
        g3 = fmaf(v.z, w20, g3); g3 = fmaf(v.w, w21, g3); g3 = fmaf(vp,  w22, g3);
    }
    const float is2 = 0.70710678118654752f;
    float4 ov;
    ov.x = 0.5f * a0 * (1.f + erff(a0 * is2)) * g0;
    ov.y = 0.5f * a1 * (1.f + erff(a1 * is2)) * g1;
    ov.z = 0.5f * a2 * (1.f + erff(a2 * is2)) * g2;
    ov.w = 0.5f * a3 * (1.f + erff(a3 * is2)) * g3;
    *(float4*)(out + ((size_t)b * HID + j) * HW + p4) = ov;
}

// Precompute 1/||k|| per (b, head, pixel); 4 pixels/thread.
__global__ __launch_bounds__(256) void knorm(
    const float* __restrict__ qkv, float* __restrict__ rk)
{
    int t = blockIdx.x * 256 + threadIdx.x;    // [0, B*NH*HW/4)
    int e = t * 4;
    int b = e / (NH * HW);
    int rem = e - b * (NH * HW);
    int h = rem / HW, p = rem & (HW - 1);
    const float* kp = qkv + ((size_t)b * C3 + CD + h * HD) * HW + p;
    float4 s = {0.f,0.f,0.f,0.f};
    #pragma unroll
    for (int d = 0; d < HD; ++d) {
        float4 v = *(const float4*)(kp + (size_t)d * HW);
        s.x = fmaf(v.x, v.x, s.x); s.y = fmaf(v.y, v.y, s.y);
        s.z = fmaf(v.z, v.z, s.z); s.w = fmaf(v.w, v.w, s.w);
    }
    float4 ov;
    ov.x = 1.f / fmaxf(sqrtf(s.x), 1e-12f);
    ov.y = 1.f / fmaxf(sqrtf(s.y), 1e-12f);
    ov.z = 1.f / fmaxf(sqrtf(s.z), 1e-12f);
    ov.w = 1.f / fmaxf(sqrtf(s.w), 1e-12f);
    *(float4*)(rk + e) = ov;
}

// ---------------------------------------------------------------------------
// Neighborhood attention, K=7, edge-clamped windows, RPB, l2-normed q/k.
// One thread per (b, head, pixel); 16x16 pixel tile per block for locality.
// Scores kept in 49 statically-indexed registers (full unroll).
// ---------------------------------------------------------------------------
__global__ __launch_bounds__(256) void natten(
    const float* __restrict__ qkv, const float* __restrict__ rknorm,
    const float* __restrict__ rpb, const float* __restrict__ temp,
    float* __restrict__ out)
{
    __shared__ float srpb[169];                // 13x13 RPB for this head
    int bh = blockIdx.z;
    int b = bh / NH, head = bh % NH;
    if (threadIdx.x < 169) srpb[threadIdx.x] = rpb[head * 169 + threadIdx.x];
    __syncthreads();

    int i = blockIdx.y * 16 + (threadIdx.x >> 4);
    int j = blockIdx.x * 16 + (threadIdx.x & 15);
    const float* qp = qkv + ((size_t)b * C3 + head * HD) * HW + i * WD + j;
    const float* kp = qkv + ((size_t)b * C3 + CD   + head * HD) * HW;
    const float* vp = qkv + ((size_t)b * C3 + 2*CD + head * HD) * HW;
    const float* rkp = rknorm + ((size_t)b * NH + head) * HW;
    float T = temp[head];

    // q load + l2 normalize
    float q[HD]; float qn = 0.f;
    #pragma unroll
    for (int d = 0; d < HD; ++d) { q[d] = qp[(size_t)d * HW]; qn = fmaf(q[d], q[d], qn); }
    qn = 1.f / fmaxf(sqrtf(qn), 1e-12f);
    #pragma unroll
    for (int d = 0; d < HD; ++d) q[d] *= qn;

    int ri0 = min(max(i - 3, 0), HT - KK);
    int cj0 = min(max(j - 3, 0), WD - KK);
    int bi0 = i - ri0 + 6;                     // rpb row base; row for o: bi0 - o/7
    int bj0 = j - cj0 + 6;

    // pass 1: scores (precomputed 1/||k||), track max
    float s[NNB]; float m = -1e30f;
    #pragma unroll
    for (int o = 0; o < NNB; ++o) {
        int r = ri0 + o / KK, c = cj0 + o % KK;
        const float* kk = kp + r * WD + c;
        float dot = 0.f;
        #pragma unroll
        for (int d = 0; d < HD; ++d)
            dot = fmaf(q[d], kk[(size_t)d * HW], dot);
        float sv = (dot * rkp[r * WD + c]
                    + srpb[(bi0 - o / KK) * 13 + (bj0 - o % KK)]) * T;
        s[o] = sv;
        m = fmaxf(m, sv);
    }
    // pass 2: softmax weights (fast exp)
    float l = 0.f;
    #pragma unroll
    for (int o = 0; o < NNB; ++o) { float pv = __expf(s[o] - m); s[o] = pv; l += pv; }
    float inv = 1.f / l;
    // pass 3: AV
    float ov[HD];
    #pragma unroll
    for (int d = 0; d < HD; ++d) ov[d] = 0.f;
    #pragma unroll
    for (int o = 0; o < NNB; ++o) {
        int r = ri0 + o / KK, c = cj0 + o % KK;
        const float* vv = vp + r * WD + c;
        float pv = s[o];
        #pragma unroll
        for (int d = 0; d < HD; ++d) ov[d] = fmaf(pv, vv[(size_t)d * HW], ov[d]);
    }
    float* op = out + ((size_t)b * CD + head * HD) * HW + i * WD + j;
    #pragma unroll
    for (int d = 0; d < HD; ++d) op[(size_t)d * HW] = ov[d] * inv;
}

// ---------------------------------------------------------------------------
extern "C" void kernel_launch(void* const* d_in, const int* in_sizes, int n_in,
                              void* d_out, int out_size, void* d_ws, size_t ws_size,
                              hipStream_t stream)
{
    const float* x        = (const float*)d_in[0];
    const float* ln1_w    = (const float*)d_in[1];
    const float* ln1_b    = (const float*)d_in[2];
    const float* qkv_w    = (const float*)d_in[3];
    const float* qkv_b    = (const float*)d_in[4];
    const float* qkv_dw_w = (const float*)d_in[5];
    const float* qkv_dw_b = (const float*)d_in[6];
    const float* rpb      = (const float*)d_in[7];
    const float* temp     = (const float*)d_in[8];
    const float* proj_w   = (const float*)d_in[9];
    const float* proj_b   = (const float*)d_in[10];
    const float* ln2_w    = (const float*)d_in[11];
    const float* ln2_b    = (const float*)d_in[12];
    const float* pin_w    = (const float*)d_in[13];
    const float* dw_w     = (const float*)d_in[14];
    const float* pout_w   = (const float*)d_in[15];
    const float* beta     = (const float*)d_in[16];
    const float* gamma    = (const float*)d_in[17];
    float* out = (float*)d_out;
    float* f   = (float*)d_ws;
    (void)in_sizes; (void)n_in; (void)out_size; (void)ws_size;

    // workspace layout (floats); total ~233 MiB
    float* W1T = f;                  // 96*288  = 27648   (qkv, LN1-folded, transposed)
    float* W2T = W1T + 27648;        // 96*512  = 49152   (pin, LN2-folded, transposed, padded)
    float* WPT = W2T + 49152;        // 96*96   = 9216    (proj, transposed)
    float* WOT = WPT + 9216;         // 255*96  = 24480   (pout, transposed)
    float* S1  = WOT + 24480;        // 512 each
    float* B1  = S1 + 512;
    float* S2  = B1 + 512;
    float* B2  = S2 + 512;
    float* MU  = B2 + 512;           // 65536
    float* RS  = MU + 65536;         // 65536
    float* R1  = f + 262144;         // 18,874,368 : qkv_pre; later ffn_pre (spans R1+R2)
    float* R2  = R1 + 18874368;      // 18,874,368 : qkv (post-dw)
    float* R3  = R2 + 18874368;      // 16,711,680 : attn_out (6.3M floats) then gated
    float* R4  = R3 + 16711680;      //  6,291,456 : x2 (post-attention residual)
    float* RK  = R1;                 // 393,216 : 1/||k||, aliased into R1 (dead
                                     //   between dwconv output and ffn conv)

    // 1. fold LN1/LN2 into conv weights; transpose all conv weights
    prep_weights<<<dim3(2), dim3(256), 0, stream>>>(
        qkv_w, qkv_b, ln1_w, ln1_b, pin_w, ln2_w, ln2_b, proj_w, pout_w,
        W1T, S1, B1, W2T, S2, B2, WPT, WOT);
    // 2. LN1 stats
    ln_stats<<<dim3(64), dim3(256), 0, stream>>>(x, MU, RS);
    // 3. qkv_pre = conv1x1(LN1(x))  [B,288,HW]
    conv1x1<0><<<dim3(18, 64), dim3(256), 0, stream>>>(
        x, W1T, CD, C3, C3, S1, B1, MU, RS, nullptr, nullptr, R1);
    // 4. depthwise 3x3 + bias
    dwconv3x3<<<dim3(16, NB_B * C3), dim3(256), 0, stream>>>(
        R1, qkv_dw_w, qkv_dw_b, R2, C3);
    // 4b. k norms (R1's qkv_pre is dead now; RK aliases its head)
    knorm<<<dim3(384), dim3(256), 0, stream>>>(R2, RK);
    // 5. neighborhood attention -> [B,96,HW]
    natten<<<dim3(8, 8, NB_B * NH), dim3(256), 0, stream>>>(R2, RK, rpb, temp, R3);
    // 6. x2 = x + (proj(attn)+proj_b)*beta
    conv1x1<1><<<dim3(6, 64), dim3(256), 0, stream>>>(
        R3, WPT, CD, CD, CD, nullptr, proj_b, nullptr, nullptr, x, beta, R4);
    // 7. LN2 stats
    ln_stats<<<dim3(64), dim3(256), 0, stream>>>(R4, MU, RS);
    // 8. ffn_pre = conv1x1(LN2(x2))  [B,510,HW]
    conv1x1<0><<<dim3(32, 64), dim3(256), 0, stream>>>(
        R4, W2T, CD, HID2, 512, S2, B2, MU, RS, nullptr, nullptr, R1);
    // 9. gated = gelu(dw(x1)) * dw(x2)  [B,255,HW]
    dw_gate<<<dim3(16, NB_B * HID), dim3(256), 0, stream>>>(R1, dw_w, R3);
    // 10. out = x2 + pout(gated)*gamma
    conv1x1<2><<<dim3(6, 64), dim3(256), 0, stream>>>(
        R3, WOT, HID, CD, CD, nullptr, nullptr, nullptr, nullptr, R4, gamma, out);
}